// Round 5
// baseline (892.887 us; speedup 1.0000x reference)
//
#include <hip/hip_runtime.h>

// SVSAlgorithm: per-pixel sequential threshold recurrence over T frames,
// fused with 3x3 constant-kernel "DiffErosion" conv + relu epilogue.
//
// Single-launch producer/consumer design:
//  - blocks [0, 320): scan role. 64 threads, one pixel-chain each; full-T
//    state-only scan with 32-deep prefetch; writes (HT,LT) snapshots every
//    SNAP=128 frames into d_ws, then release-fence + atomic flag increment.
//  - blocks [320, 2240): compute role. 16x16 tile (14x14 interior + halo),
//    one block per (tile, 128-frame slice). Slice 0 starts immediately;
//    slice k>0 spins (thread 0, s_sleep) on flags[k-1]==320 with a realtime
//    timeout -> bit-exact self-warm-up fallback (correct under ANY dispatch
//    order; snapshot path and fallback path compute identical f32 chains).
//  - sigmoid via exp2(fma)+v_rcp; conv == box-sum (all 9 weights equal):
//    vertical = 2 LDS reads + own register, horizontal via DPP row_shr/shl.
//  - LDS laid out sm[row][frame][col] so a wave's 4 row-clusters land at
//    bank shifts {0,8,16,24} -> <=2-way (free), vs 4-way at the old layout.
//  - XCD-grouped compute-block remap keeps bx-adjacent tiles on one XCD L2
//    so partial 128B output lines merge before writeback.
//  - state updates replicate reference f32 op order exactly.

#define TILE_W 16
#define TILE_H 16
#define IN_W 14
#define IN_H 14
#define BUF 8        // frames per LDS stage in compute role
#define PRE 32       // prefetch depth in scan role (2*PRE divides 2048, 128%PRE==0)

constexpr int T_FRAMES = 2048;
constexpr int H_IMG = 128;
constexpr int W_IMG = 160;
constexpr int HW = H_IMG * W_IMG;
constexpr int SNAP = 128;                        // snapshot period
constexpr int NSNAP = T_FRAMES / SNAP - 1;       // 15 snapshots (t=128..1920)
constexpr int NSLICE = T_FRAMES / SNAP;          // 16
constexpr int SCAN_BLOCKS = HW / 64;             // 320
constexpr int NTILE = 12 * 10;                   // 120 tiles per slice
constexpr int COMPUTE_BLOCKS = NTILE * NSLICE;   // 1920
constexpr size_t FLAGS_BYTES = 64;
constexpr size_t WS_NEEDED = FLAGS_BYTES + (size_t)NSNAP * HW * sizeof(float2);
constexpr float C1 = 721.3475204444817f;         // 500 * log2(e)
constexpr unsigned long long SPIN_TIMEOUT = 200000ull;  // ~2ms of 100MHz realtime ticks

__device__ __forceinline__ float dpp_from_left(float v) {   // lane n <- lane n-1 (16-lane rows)
    return __int_as_float(__builtin_amdgcn_update_dpp(0, __float_as_int(v), 0x111, 0xF, 0xF, true));
}
__device__ __forceinline__ float dpp_from_right(float v) {  // lane n <- lane n+1
    return __int_as_float(__builtin_amdgcn_update_dpp(0, __float_as_int(v), 0x101, 0xF, 0xF, true));
}

__global__ __launch_bounds__(256)
void svs_mono(const float* __restrict__ x, const float* __restrict__ params,
              const float* __restrict__ HT0, const float* __restrict__ LT0,
              const float* __restrict__ kern,
              float2* __restrict__ snap, int* __restrict__ flags,
              float* __restrict__ out)
{
    const float dC = params[0];
    const float dO = params[1];

    if (blockIdx.x < SCAN_BLOCKS) {
        // ---------------- scan role ----------------
        const int tid = threadIdx.x;
        if (tid >= 64) return;                    // 1 wave per scan block
        const int pix = (int)blockIdx.x * 64 + tid;

        float HT = HT0[pix];
        float LT = LT0[pix];
        const float* xp = x + pix;

        float va[PRE], vb[PRE];
        #pragma unroll
        for (int i = 0; i < PRE; ++i) va[i] = xp[i * HW];

        for (int t = 0; t < T_FRAMES; t += 2 * PRE) {
            #pragma unroll
            for (int i = 0; i < PRE; ++i) vb[i] = xp[(t + PRE + i) * HW];
            #pragma unroll
            for (int i = 0; i < PRE; ++i) {
                const float img = va[i];
                HT = ((img - HT) > 0.0f) ? (HT + dO) : (HT - dC);
                LT = ((LT - img) > 0.0f) ? (LT - dO) : (LT + dC);
            }
            if ((((t + PRE) & (SNAP - 1)) == 0)) {
                const int k = (t + PRE) / SNAP;
                if (k <= NSNAP) {
                    snap[(k - 1) * HW + pix] = make_float2(HT, LT);
                    __threadfence();              // release: snap visible before flag
                    if (tid == 0)
                        __atomic_fetch_add(&flags[k - 1], 1, __ATOMIC_RELAXED);
                }
            }
            if (t + 2 * PRE < T_FRAMES) {
                #pragma unroll
                for (int i = 0; i < PRE; ++i) va[i] = xp[(t + 2 * PRE + i) * HW];
            }
            #pragma unroll
            for (int i = 0; i < PRE; ++i) {
                const float img = vb[i];
                HT = ((img - HT) > 0.0f) ? (HT + dO) : (HT - dC);
                LT = ((LT - img) > 0.0f) ? (LT - dO) : (LT + dC);
            }
            if ((((t + 2 * PRE) & (SNAP - 1)) == 0)) {
                const int k = (t + 2 * PRE) / SNAP;
                if (k <= NSNAP) {
                    snap[(k - 1) * HW + pix] = make_float2(HT, LT);
                    __threadfence();
                    if (tid == 0)
                        __atomic_fetch_add(&flags[k - 1], 1, __ATOMIC_RELAXED);
                }
            }
        }
        return;
    }

    // ---------------- compute role ----------------
    // XCD-grouped remap: contiguous chunks of compute-block id per XCD so
    // adjacent-bx tiles (sharing output cache lines) land on one XCD L2.
    const int cb = (int)blockIdx.x - SCAN_BLOCKS;
    const int w  = (cb & 7) * (COMPUTE_BLOCKS / 8) + (cb >> 3);   // bijective
    const int bx = w % 12;
    const int by = (w / 12) % 10;
    const int slice = w / NTILE;

    const int tx = threadIdx.x & 15;
    const int ty = threadIdx.x >> 4;
    const int gx = bx * IN_W + tx - 1;
    const int gy = by * IN_H + ty - 1;
    const int t0 = slice * SNAP;

    const bool valid = (gx >= 0) & (gx < W_IMG) & (gy >= 0) & (gy < H_IMG);
    const int cx = min(max(gx, 0), W_IMG - 1);
    const int cy = min(max(gy, 0), H_IMG - 1);
    const int pix = cy * W_IMG + cx;

    const float dHot = params[2];
    const float kw   = kern[4];        // all 9 weights equal (2/9)
    const float c0   = dHot * C1;      // exp2 arg = fma(a, -C1, c0)
    const float* xp  = x + pix;
    float* op = out + pix;

    // sm[row][frame][col]: row stride 136 floats == 8 mod 32 banks ->
    // wave's 4 row-clusters at bank shifts {0,8,16,24}: <=2-way (free).
    __shared__ float sm[TILE_H][BUF][TILE_W + 1];
    __shared__ int sReady;

    float HT, LT;
    if (slice == 0) {
        HT = valid ? HT0[pix] : 0.0f;
        LT = valid ? LT0[pix] : 0.0f;
    } else {
        if (threadIdx.x == 0) {
            int got = __atomic_load_n(&flags[slice - 1], __ATOMIC_RELAXED);
            if (got < SCAN_BLOCKS) {
                const unsigned long long ts = __builtin_amdgcn_s_memrealtime();
                do {
                    __builtin_amdgcn_s_sleep(32);
                    got = __atomic_load_n(&flags[slice - 1], __ATOMIC_RELAXED);
                } while (got < SCAN_BLOCKS &&
                         (__builtin_amdgcn_s_memrealtime() - ts) < SPIN_TIMEOUT);
            }
            sReady = (got >= SCAN_BLOCKS) ? 1 : 0;
        }
        __syncthreads();
        if (sReady) {
            __threadfence();                      // acquire: order snap reads after flag
            const float2 s = snap[(slice - 1) * HW + pix];
            HT = valid ? s.x : 0.0f;
            LT = valid ? s.y : 0.0f;
        } else {
            // timeout fallback: bit-exact self-warm-up from t=0 (identical
            // f32 chain as scan role -> identical state, any dispatch order)
            HT = valid ? HT0[pix] : 0.0f;
            LT = valid ? LT0[pix] : 0.0f;
            for (int t = 0; t < t0; t += 8) {
                float v[8];
                #pragma unroll
                for (int i = 0; i < 8; ++i) v[i] = xp[(t + i) * HW];
                #pragma unroll
                for (int i = 0; i < 8; ++i) {
                    const float img = v[i];
                    HT = ((img - HT) > 0.0f) ? (HT + dO) : (HT - dC);
                    LT = ((LT - img) > 0.0f) ? (LT - dO) : (LT + dC);
                }
            }
        }
    }

    const bool doOut = (tx >= 1) & (tx <= IN_W) & (ty >= 1) & (ty <= IN_H) & valid;
    const int ym = max(ty - 1, 0);
    const int yp = min(ty + 1, TILE_H - 1);

    for (int tb = t0; tb < t0 + SNAP; tb += BUF) {
        float v[BUF], hot[BUF];
        #pragma unroll
        for (int i = 0; i < BUF; ++i) v[i] = xp[(tb + i) * HW];
        #pragma unroll
        for (int i = 0; i < BUF; ++i) {
            const float img = v[i];
            const float aH = img - HT;
            const float eH = __builtin_amdgcn_exp2f(fmaf(aH, -C1, c0));
            const float hH = __builtin_amdgcn_rcpf(1.0f + eH);
            HT = (aH > 0.0f) ? (HT + dO) : (HT - dC);
            const float aL = LT - img;
            const float eL = __builtin_amdgcn_exp2f(fmaf(aL, -C1, c0));
            const float hL = __builtin_amdgcn_rcpf(1.0f + eL);
            LT = (aL > 0.0f) ? (LT - dO) : (LT + dC);
            hot[i] = valid ? (hH + hL) : 1.0f;
            sm[ty][i][tx] = hot[i];
        }
        __syncthreads();
        #pragma unroll
        for (int i = 0; i < BUF; ++i) {
            const float r0 = sm[ym][i][tx];
            const float r1 = sm[yp][i][tx];
            const float vs = r0 + hot[i] + r1;               // vertical box sum
            const float S  = vs + dpp_from_left(vs) + dpp_from_right(vs);
            float o = fmaf(S, kw, -1.0f);                    // 1 - kw*(9-S) = kw*S - 1
            o = fmaxf(o, 0.0f);
            if (doOut) op[(tb + i) * HW] = o;
        }
        __syncthreads();
    }
}

// ---------------- Fallback: fused kernel (if ws too small) ----------------
#define NCHUNK 8
constexpr int CHUNK = T_FRAMES / NCHUNK;

__global__ __launch_bounds__(256)
void svs_fused(const float* __restrict__ x, const float* __restrict__ params,
               const float* __restrict__ HT0, const float* __restrict__ LT0,
               const float* __restrict__ kern, float* __restrict__ out)
{
    const int tx = threadIdx.x & 15;
    const int ty = threadIdx.x >> 4;
    const int gx = (int)blockIdx.x * IN_W + tx - 1;
    const int gy = (int)blockIdx.y * IN_H + ty - 1;
    const int chunk = (NCHUNK - 1) - (int)blockIdx.z;

    const bool valid = (gx >= 0) & (gx < W_IMG) & (gy >= 0) & (gy < H_IMG);
    const int cx = min(max(gx, 0), W_IMG - 1);
    const int cy = min(max(gy, 0), H_IMG - 1);
    const int pix = cy * W_IMG + cx;

    const float dC   = params[0];
    const float dO   = params[1];
    const float dHot = params[2];
    const float kw   = kern[4];

    float HT = valid ? HT0[pix] : 0.0f;
    float LT = valid ? LT0[pix] : 0.0f;

    const float* xp = x + pix;
    const int t0 = chunk * CHUNK;

    for (int t = 0; t < t0; t += BUF) {
        float v[BUF];
        #pragma unroll
        for (int i = 0; i < BUF; ++i) v[i] = xp[(t + i) * HW];
        #pragma unroll
        for (int i = 0; i < BUF; ++i) {
            const float img = v[i];
            HT = ((img - HT) > 0.0f) ? (HT + dO) : (HT - dC);
            LT = ((LT - img) > 0.0f) ? (LT - dO) : (LT + dC);
        }
    }

    __shared__ float sm[TILE_H][BUF][TILE_W + 1];
    const bool doOut = (tx >= 1) & (tx <= IN_W) & (ty >= 1) & (ty <= IN_H) & valid;
    const int ym = max(ty - 1, 0);
    const int yp = min(ty + 1, TILE_H - 1);
    const float c0 = dHot * C1;
    float* op = out + pix;

    for (int tb = t0; tb < t0 + CHUNK; tb += BUF) {
        float v[BUF], hot[BUF];
        #pragma unroll
        for (int i = 0; i < BUF; ++i) v[i] = xp[(tb + i) * HW];
        #pragma unroll
        for (int i = 0; i < BUF; ++i) {
            const float img = v[i];
            const float aH = img - HT;
            const float eH = __builtin_amdgcn_exp2f(fmaf(aH, -C1, c0));
            const float hH = __builtin_amdgcn_rcpf(1.0f + eH);
            HT = (aH > 0.0f) ? (HT + dO) : (HT - dC);
            const float aL = LT - img;
            const float eL = __builtin_amdgcn_exp2f(fmaf(aL, -C1, c0));
            const float hL = __builtin_amdgcn_rcpf(1.0f + eL);
            LT = (aL > 0.0f) ? (LT - dO) : (LT + dC);
            hot[i] = valid ? (hH + hL) : 1.0f;
            sm[ty][i][tx] = hot[i];
        }
        __syncthreads();
        #pragma unroll
        for (int i = 0; i < BUF; ++i) {
            const float r0 = sm[ym][i][tx];
            const float r1 = sm[yp][i][tx];
            const float vs = r0 + hot[i] + r1;
            const float S  = vs + dpp_from_left(vs) + dpp_from_right(vs);
            float o = fmaf(S, kw, -1.0f);
            o = fmaxf(o, 0.0f);
            if (doOut) op[(tb + i) * HW] = o;
        }
        __syncthreads();
    }
}

extern "C" void kernel_launch(void* const* d_in, const int* in_sizes, int n_in,
                              void* d_out, int out_size, void* d_ws, size_t ws_size,
                              hipStream_t stream) {
    const float* x      = (const float*)d_in[0];
    const float* params = (const float*)d_in[1];
    const float* HT0p   = (const float*)d_in[2];
    const float* LT0p   = (const float*)d_in[3];
    const float* kern   = (const float*)d_in[4];
    float* out = (float*)d_out;

    if (ws_size >= WS_NEEDED) {
        int* flags = (int*)d_ws;
        float2* snap = (float2*)((char*)d_ws + FLAGS_BYTES);
        (void)hipMemsetAsync(d_ws, 0, FLAGS_BYTES, stream);   // capture-safe, in-stream
        svs_mono<<<dim3(SCAN_BLOCKS + COMPUTE_BLOCKS), dim3(256), 0, stream>>>(
            x, params, HT0p, LT0p, kern, snap, flags, out);
    } else {
        dim3 grid((W_IMG + IN_W - 1) / IN_W, (H_IMG + IN_H - 1) / IN_H, NCHUNK);
        svs_fused<<<grid, dim3(256), 0, stream>>>(x, params, HT0p, LT0p, kern, out);
    }
}

// Round 6
// 153.042 us; speedup vs baseline: 5.8343x; 5.8343x over previous
//
#include <hip/hip_runtime.h>

// SVSAlgorithm: per-pixel sequential threshold recurrence over T frames,
// fused with 3x3 constant-kernel "DiffErosion" conv + relu epilogue.
//
// Two-launch design (R5's single-launch producer/consumer regressed: merged
// regalloc spilled the scan's prefetch arrays at VGPR=60 -> scratch traffic):
//  L1 svs_scan<SNAP>: 64-thread blocks, 1 pixel-chain/thread, full-T state
//     scan. 4-deep rotating batch pipeline (4x32 named register arrays,
//     issue 3 batches ahead) -> ~63 outstanding loads/wave, ~5MB in flight
//     device-wide ~ BW*latency. Snapshots (HT,LT) every SNAP frames to d_ws.
//     Own kernel => own regalloc, __launch_bounds__(64,1), no spill.
//  L2 svs_compute<SNAP>: 16x16 tile (14x14 interior + halo recompute), one
//     block per (tile, SNAP-frame slice). SNAP=64 -> 3840 blocks = 15/CU ->
//     occupancy saturates the 8-block/CU thread limit (R3 was grid-limited
//     at 50%). Sigmoid via exp2(fma)+v_rcp; conv == box-sum (all 9 weights
//     equal): vertical = 2 LDS reads + own register, horizontal via DPP
//     row_shr/row_shl. LDS sm[row][frame][col] (row stride 136 == 8 mod 32
//     banks -> <=2-way). XCD-grouped block remap for output-line merging.
//  State updates replicate reference f32 op order exactly.
//  ws ladder: SNAP=64 (5.1MB) -> SNAP=128 (2.4MB) -> fused fallback.

#define TILE_W 16
#define TILE_H 16
#define IN_W 14
#define IN_H 14
#define BUF 8        // frames per LDS stage in compute pass
#define B32 32       // scan batch size

constexpr int T_FRAMES = 2048;
constexpr int H_IMG = 128;
constexpr int W_IMG = 160;
constexpr int HW = H_IMG * W_IMG;
constexpr float C1 = 721.3475204444817f;         // 500 * log2(e)

constexpr size_t ws_needed(int snap) {
    return (size_t)(T_FRAMES / snap - 1) * HW * sizeof(float2);
}

__device__ __forceinline__ float dpp_from_left(float v) {   // lane n <- lane n-1 (16-lane rows)
    return __int_as_float(__builtin_amdgcn_update_dpp(0, __float_as_int(v), 0x111, 0xF, 0xF, true));
}
__device__ __forceinline__ float dpp_from_right(float v) {  // lane n <- lane n+1
    return __int_as_float(__builtin_amdgcn_update_dpp(0, __float_as_int(v), 0x101, 0xF, 0xF, true));
}

// ---------------- L1: state-only scan, 4-deep pipelined prefetch ----------
#define ISSUE_BATCH(V, F)                          \
    _Pragma("unroll")                              \
    for (int i = 0; i < B32; ++i) V[i] = xp[((F) + i) * HW];

#define COMP_BATCH(V)                              \
    _Pragma("unroll")                              \
    for (int i = 0; i < B32; ++i) {                \
        const float img = V[i];                    \
        HT = ((img - HT) > 0.0f) ? (HT + dO) : (HT - dC); \
        LT = ((LT - img) > 0.0f) ? (LT - dO) : (LT + dC); \
    }

#define SNAPSHOT(F)                                \
    if (((F) % SNAP_) == 0) {                      \
        const int k = (F) / SNAP_ - 1;             \
        if (k < T_FRAMES / SNAP_ - 1)              \
            snap[k * HW + pix] = make_float2(HT, LT); \
    }

template <int SNAP_>
__global__ __launch_bounds__(64, 1)
void svs_scan(const float* __restrict__ x, const float* __restrict__ params,
              const float* __restrict__ HT0, const float* __restrict__ LT0,
              float2* __restrict__ snap)
{
    const int pix = (int)blockIdx.x * 64 + (int)threadIdx.x;  // 320 blocks
    const float dC = params[0];
    const float dO = params[1];

    float HT = HT0[pix];
    float LT = LT0[pix];
    const float* xp = x + pix;

    float v0[B32], v1[B32], v2[B32], v3[B32];
    ISSUE_BATCH(v0, 0)
    ISSUE_BATCH(v1, B32)
    ISSUE_BATCH(v2, 2 * B32)
    ISSUE_BATCH(v3, 3 * B32)

    for (int t = 0; t < T_FRAMES; t += 4 * B32) {
        const bool more = (t + 4 * B32) < T_FRAMES;
        COMP_BATCH(v0)
        if (more) { ISSUE_BATCH(v0, t + 4 * B32) }
        COMP_BATCH(v1)
        SNAPSHOT(t + 2 * B32)
        if (more) { ISSUE_BATCH(v1, t + 5 * B32) }
        COMP_BATCH(v2)
        if (more) { ISSUE_BATCH(v2, t + 6 * B32) }
        COMP_BATCH(v3)
        SNAPSHOT(t + 4 * B32)
        if (more) { ISSUE_BATCH(v3, t + 7 * B32) }
    }
}

// ---------------- L2: per-slice fused compute -----------------------------
template <int SNAP_>
__global__ __launch_bounds__(256)
void svs_compute(const float* __restrict__ x, const float* __restrict__ params,
                 const float* __restrict__ HT0, const float* __restrict__ LT0,
                 const float* __restrict__ kern, const float2* __restrict__ snap,
                 float* __restrict__ out)
{
    constexpr int NSLICE_ = T_FRAMES / SNAP_;
    constexpr int TOTAL_ = 120 * NSLICE_;
    // XCD-grouped remap: contiguous chunks of linear block id per XCD so
    // adjacent-bx tiles (sharing output cache lines) land on one XCD L2.
    const int lin = (int)blockIdx.x + 12 * (int)blockIdx.y + 120 * (int)blockIdx.z;
    const int w   = (lin & 7) * (TOTAL_ / 8) + (lin >> 3);   // TOTAL_%8==0 -> bijective
    const int bx  = w % 12;
    const int by  = (w / 12) % 10;
    const int slice = w / 120;

    const int tx = threadIdx.x & 15;
    const int ty = threadIdx.x >> 4;
    const int gx = bx * IN_W + tx - 1;
    const int gy = by * IN_H + ty - 1;
    const int t0 = slice * SNAP_;

    const bool valid = (gx >= 0) & (gx < W_IMG) & (gy >= 0) & (gy < H_IMG);
    const int cx = min(max(gx, 0), W_IMG - 1);
    const int cy = min(max(gy, 0), H_IMG - 1);
    const int pix = cy * W_IMG + cx;

    const float dC   = params[0];
    const float dO   = params[1];
    const float dHot = params[2];
    const float kw   = kern[4];        // all 9 weights equal (2/9)
    const float c0   = dHot * C1;      // exp2 arg = fma(a, -C1, c0)

    float HT, LT;
    if (slice == 0) {
        HT = valid ? HT0[pix] : 0.0f;
        LT = valid ? LT0[pix] : 0.0f;
    } else {
        const float2 s = snap[(slice - 1) * HW + pix];
        HT = valid ? s.x : 0.0f;
        LT = valid ? s.y : 0.0f;
    }

    // sm[row][frame][col]: row stride 136 floats == 8 mod 32 banks ->
    // wave's 4 row-clusters at bank shifts {0,8,16,24}: <=2-way (free).
    __shared__ float sm[TILE_H][BUF][TILE_W + 1];

    const bool doOut = (tx >= 1) & (tx <= IN_W) & (ty >= 1) & (ty <= IN_H) & valid;
    const int ym = max(ty - 1, 0);
    const int yp = min(ty + 1, TILE_H - 1);
    const float* xp = x + pix;
    float* op = out + pix;

    for (int tb = t0; tb < t0 + SNAP_; tb += BUF) {
        float v[BUF], hot[BUF];
        #pragma unroll
        for (int i = 0; i < BUF; ++i) v[i] = xp[(tb + i) * HW];
        #pragma unroll
        for (int i = 0; i < BUF; ++i) {
            const float img = v[i];
            const float aH = img - HT;
            const float eH = __builtin_amdgcn_exp2f(fmaf(aH, -C1, c0));
            const float hH = __builtin_amdgcn_rcpf(1.0f + eH);
            HT = (aH > 0.0f) ? (HT + dO) : (HT - dC);
            const float aL = LT - img;
            const float eL = __builtin_amdgcn_exp2f(fmaf(aL, -C1, c0));
            const float hL = __builtin_amdgcn_rcpf(1.0f + eL);
            LT = (aL > 0.0f) ? (LT - dO) : (LT + dC);
            hot[i] = valid ? (hH + hL) : 1.0f;
            sm[ty][i][tx] = hot[i];
        }
        __syncthreads();
        #pragma unroll
        for (int i = 0; i < BUF; ++i) {
            const float r0 = sm[ym][i][tx];
            const float r1 = sm[yp][i][tx];
            const float vs = r0 + hot[i] + r1;               // vertical box sum
            const float S  = vs + dpp_from_left(vs) + dpp_from_right(vs);
            float o = fmaf(S, kw, -1.0f);                    // 1 - kw*(9-S) = kw*S - 1
            o = fmaxf(o, 0.0f);
            if (doOut) op[(tb + i) * HW] = o;
        }
        __syncthreads();
    }
}

// ---------------- Fallback: fused kernel (if ws too small) ----------------
#define NCHUNK 8
constexpr int CHUNK = T_FRAMES / NCHUNK;

__global__ __launch_bounds__(256)
void svs_fused(const float* __restrict__ x, const float* __restrict__ params,
               const float* __restrict__ HT0, const float* __restrict__ LT0,
               const float* __restrict__ kern, float* __restrict__ out)
{
    const int tx = threadIdx.x & 15;
    const int ty = threadIdx.x >> 4;
    const int gx = (int)blockIdx.x * IN_W + tx - 1;
    const int gy = (int)blockIdx.y * IN_H + ty - 1;
    const int chunk = (NCHUNK - 1) - (int)blockIdx.z;

    const bool valid = (gx >= 0) & (gx < W_IMG) & (gy >= 0) & (gy < H_IMG);
    const int cx = min(max(gx, 0), W_IMG - 1);
    const int cy = min(max(gy, 0), H_IMG - 1);
    const int pix = cy * W_IMG + cx;

    const float dC   = params[0];
    const float dO   = params[1];
    const float dHot = params[2];
    const float kw   = kern[4];

    float HT = valid ? HT0[pix] : 0.0f;
    float LT = valid ? LT0[pix] : 0.0f;

    const float* xp = x + pix;
    const int t0 = chunk * CHUNK;

    for (int t = 0; t < t0; t += BUF) {
        float v[BUF];
        #pragma unroll
        for (int i = 0; i < BUF; ++i) v[i] = xp[(t + i) * HW];
        #pragma unroll
        for (int i = 0; i < BUF; ++i) {
            const float img = v[i];
            HT = ((img - HT) > 0.0f) ? (HT + dO) : (HT - dC);
            LT = ((LT - img) > 0.0f) ? (LT - dO) : (LT + dC);
        }
    }

    __shared__ float sm[TILE_H][BUF][TILE_W + 1];
    const bool doOut = (tx >= 1) & (tx <= IN_W) & (ty >= 1) & (ty <= IN_H) & valid;
    const int ym = max(ty - 1, 0);
    const int yp = min(ty + 1, TILE_H - 1);
    const float c0 = dHot * C1;
    float* op = out + pix;

    for (int tb = t0; tb < t0 + CHUNK; tb += BUF) {
        float v[BUF], hot[BUF];
        #pragma unroll
        for (int i = 0; i < BUF; ++i) v[i] = xp[(tb + i) * HW];
        #pragma unroll
        for (int i = 0; i < BUF; ++i) {
            const float img = v[i];
            const float aH = img - HT;
            const float eH = __builtin_amdgcn_exp2f(fmaf(aH, -C1, c0));
            const float hH = __builtin_amdgcn_rcpf(1.0f + eH);
            HT = (aH > 0.0f) ? (HT + dO) : (HT - dC);
            const float aL = LT - img;
            const float eL = __builtin_amdgcn_exp2f(fmaf(aL, -C1, c0));
            const float hL = __builtin_amdgcn_rcpf(1.0f + eL);
            LT = (aL > 0.0f) ? (LT - dO) : (LT + dC);
            hot[i] = valid ? (hH + hL) : 1.0f;
            sm[ty][i][tx] = hot[i];
        }
        __syncthreads();
        #pragma unroll
        for (int i = 0; i < BUF; ++i) {
            const float r0 = sm[ym][i][tx];
            const float r1 = sm[yp][i][tx];
            const float vs = r0 + hot[i] + r1;
            const float S  = vs + dpp_from_left(vs) + dpp_from_right(vs);
            float o = fmaf(S, kw, -1.0f);
            o = fmaxf(o, 0.0f);
            if (doOut) op[(tb + i) * HW] = o;
        }
        __syncthreads();
    }
}

extern "C" void kernel_launch(void* const* d_in, const int* in_sizes, int n_in,
                              void* d_out, int out_size, void* d_ws, size_t ws_size,
                              hipStream_t stream) {
    const float* x      = (const float*)d_in[0];
    const float* params = (const float*)d_in[1];
    const float* HT0p   = (const float*)d_in[2];
    const float* LT0p   = (const float*)d_in[3];
    const float* kern   = (const float*)d_in[4];
    float* out = (float*)d_out;

    if (ws_size >= ws_needed(64)) {
        float2* snap = (float2*)d_ws;
        svs_scan<64><<<dim3(HW / 64), dim3(64), 0, stream>>>(x, params, HT0p, LT0p, snap);
        svs_compute<64><<<dim3(12, 10, T_FRAMES / 64), dim3(256), 0, stream>>>(
            x, params, HT0p, LT0p, kern, snap, out);
    } else if (ws_size >= ws_needed(128)) {
        float2* snap = (float2*)d_ws;
        svs_scan<128><<<dim3(HW / 64), dim3(64), 0, stream>>>(x, params, HT0p, LT0p, snap);
        svs_compute<128><<<dim3(12, 10, T_FRAMES / 128), dim3(256), 0, stream>>>(
            x, params, HT0p, LT0p, kern, snap, out);
    } else {
        dim3 grid((W_IMG + IN_W - 1) / IN_W, (H_IMG + IN_H - 1) / IN_H, NCHUNK);
        svs_fused<<<grid, dim3(256), 0, stream>>>(x, params, HT0p, LT0p, kern, out);
    }
}